// Round 17
// baseline (49.102 us; speedup 1.0000x reference)
//
#include <hip/hip_runtime.h>
#include <hip/hip_bf16.h>

#define N_PED 1024
#define H 128
#define G 8
#define K_TOT 8192
#define HALF_NB 16.0f
#define INV_CELL 0.25f
#define LISTCAP 192     // per-ped neighbor cap (mean ~105)
#define MCAP 160        // per-(block,cell) match cap (mean ~105)
#define KSPLIT 16
#define BM 64

typedef __attribute__((ext_vector_type(8))) short bf16x8;
typedef __attribute__((ext_vector_type(4))) float f32x4;

__device__ __forceinline__ unsigned map_f2u(float v) {
    unsigned u = __float_as_uint(v);
    return (u & 0x80000000u) ? ~u : (u | 0x80000000u);
}
// pooled values are >= map(0) -> unmap is a single XOR
__device__ __forceinline__ unsigned pack2x(unsigned ua, unsigned ub) {
    float2 f = {__uint_as_float(ua ^ 0x80000000u),
                __uint_as_float(ub ^ 0x80000000u)};
    union { __hip_bfloat162 h; unsigned u; } cv;
    cv.h = __float22bfloat162_rn(f);
    return cv.u;
}
__device__ __forceinline__ unsigned pack2f(float fa, float fb) {
    float2 f = {fa, fb};
    union { __hip_bfloat162 h; unsigned u; } cv;
    cv.h = __float22bfloat162_rn(f);
    return cv.u;
}
__device__ __forceinline__ void gl_lds16(const void* g, void* l) {
    __builtin_amdgcn_global_load_lds(
        (const __attribute__((address_space(1))) void*)g,
        (__attribute__((address_space(3))) void*)l, 16, 0, 0);
}

// blocks 0..63  : neighbor lists for 16 peds each, ushort entry = (j<<6)|cell
// blocks 64..191: W [8192][128] fp32 -> Wt [128][8192] bf16
__global__ __launch_bounds__(512) void prep(const float* __restrict__ pos,
                                            const float* __restrict__ W,
                                            ushort* __restrict__ lists,
                                            int* __restrict__ cntg,
                                            ushort* __restrict__ Wt) {
    __shared__ __align__(16) char smem[33024];
    const int tid = threadIdx.x;

    if (blockIdx.x < 64) {
        float2* pis  = (float2*)smem;                 // 128 B
        int*    lcnt = (int*)(smem + 128);            // 64 B
        ushort* ll   = (ushort*)(smem + 192);         // 6144 B
        const int base = blockIdx.x * 16;
        if (tid < 16) { pis[tid] = ((const float2*)pos)[base + tid]; lcnt[tid] = 0; }
        __syncthreads();
        for (int j = tid; j < N_PED; j += 512) {
            float2 pj = ((const float2*)pos)[j];
            #pragma unroll
            for (int p = 0; p < 16; ++p) {
                float rx = pj.x - pis[p].x;
                float ry = pj.y - pis[p].y;
                if (j != base + p && fabsf(rx) <= HALF_NB && fabsf(ry) <= HALF_NB) {
                    int gx = min(G - 1, max(0, (int)floorf((rx + HALF_NB) * INV_CELL)));
                    int gy = min(G - 1, max(0, (int)floorf((ry + HALF_NB) * INV_CELL)));
                    int slot = atomicAdd(&lcnt[p], 1);
                    if (slot < LISTCAP) ll[p * LISTCAP + slot] = (ushort)((j << 6) | (gy * G + gx));
                }
            }
        }
        __syncthreads();
        uint4* dst = (uint4*)(lists + (size_t)base * LISTCAP);
        for (int x = tid; x < 16 * LISTCAP / 8; x += 512) dst[x] = ((const uint4*)ll)[x];
        if (tid < 16) cntg[base + tid] = min(lcnt[tid], LISTCAP);
    } else {
        float* tile = (float*)smem;                   // [64][129]
        const int bw  = blockIdx.x - 64;
        const int k0w = bw * 64;
        for (int x = tid; x < 64 * H; x += 512) {
            int r = x >> 7, cc = x & 127;
            tile[r * 129 + cc] = W[(size_t)(k0w + r) * H + cc];
        }
        __syncthreads();
        const int col = tid >> 2;
        const int kh  = (tid & 3) * 16;
        uint tmp[8];
        #pragma unroll
        for (int t = 0; t < 8; ++t)
            tmp[t] = pack2f(tile[(kh + 2 * t) * 129 + col],
                            tile[(kh + 2 * t + 1) * 129 + col]);
        uint4* w0 = (uint4*)(Wt + (size_t)col * K_TOT + k0w + kh);
        w0[0] = *(const uint4*)&tmp[0];
        w0[1] = *(const uint4*)&tmp[4];
    }
}

// Fused pool+GEMM: block (mx, ky) = 64 peds x cells 4ky..4ky+3 (K slice 512).
// Per cell-quarter: scatter-pool into 32KB LDS (atomicMax, bank=dim -> free),
// convert in-place to swizzled bf16 A (aliases pool rows 0..31), 16 MFMAs.
// No grid materialization. LDS 65.3KB -> 2 blocks/CU.
__global__ __launch_bounds__(512, 4) void pool_gemm(const float* __restrict__ hs,
                                                    const ushort* __restrict__ lists,
                                                    const int* __restrict__ cntg,
                                                    const ushort* __restrict__ Wt,
                                                    float* __restrict__ part) {
    __shared__ __align__(16) char smem[66832];
    uint*   pool = (uint*)smem;                 // [64][128] mapped-uint, 32 KB
    ushort* Alds = (ushort*)smem;               // [64][128] bf16, 16 KB (alias!)
    char*   Bb   = smem + 32768;                // 2 x 16 KB: [128 cols][64 k] bf16
    ushort* ml   = (ushort*)(smem + 65536);     // 4 x MCAP, entry (j<<6)|p
    int*    mcnt = (int*)(smem + 65536 + 4 * MCAP * 2);

    const int mx = blockIdx.x, ky = blockIdx.y;
    const int m0 = mx * BM;
    const int kbase = ky * 512;
    const int tid  = threadIdx.x;
    const int wave = tid >> 6, lane = tid & 63;
    const int ll_  = lane & 15, lh = lane >> 4, lr8 = lane >> 3;
    const int cswz = (lane & 7) ^ (lr8 & 7);
    const int wr = wave >> 2, wc = wave & 3;

    // load own list slice into regs (ped p_own, entry stride 8)
    const int p_own = tid >> 3, su = tid & 7;
    const uint4* lp = (const uint4*)(lists + (size_t)(m0 + p_own) * LISTCAP);
    uint4 le0 = lp[su];
    uint4 le1 = lp[su + 8];
    uint4 le2 = lp[su + 16];
    const int np = cntg[m0 + p_own];
    if (tid < 4) mcnt[tid] = 0;
    __syncthreads();

    // compact this ky-group's matches into 4 per-cell lists
#define COMPACT_U4(LE, IBASE)                                                  \
    {                                                                          \
        _Pragma("unroll")                                                      \
        for (int s = 0; s < 8; ++s) {                                          \
            uint w = ((const uint*)&(LE))[s >> 1];                             \
            ushort ent = (s & 1) ? (ushort)(w >> 16) : (ushort)(w & 0xFFFFu);  \
            int idx = (IBASE) + s;                                             \
            if (idx < np) {                                                    \
                int cell = ent & 63;                                           \
                if ((cell >> 2) == ky) {                                       \
                    int q = cell & 3;                                          \
                    int slot = atomicAdd(&mcnt[q], 1);                         \
                    if (slot < MCAP)                                           \
                        ml[q * MCAP + slot] =                                  \
                            (ushort)((((int)ent >> 6) << 6) | p_own);          \
                }                                                              \
            }                                                                  \
        }                                                                      \
    }
    COMPACT_U4(le0, su * 8)
    COMPACT_U4(le1, (su + 8) * 8)
    COMPACT_U4(le2, (su + 16) * 8)
#undef COMPACT_U4
    __syncthreads();
    int nq[4];
    nq[0] = min(mcnt[0], MCAP); nq[1] = min(mcnt[1], MCAP);
    nq[2] = min(mcnt[2], MCAP); nq[3] = min(mcnt[3], MCAP);

    f32x4 acc[2][2] = {};   // accumulates across all 4 quarters

    #pragma unroll
    for (int q = 0; q < 4; ++q) {
        // issue both B halves for this quarter (drained at next syncthreads)
        {
            const ushort* Bs = Wt + kbase + q * 128 + cswz * 8;
            const size_t r0 = (size_t)(16 * wave + lr8) * K_TOT;
            const size_t r1 = (size_t)(16 * wave + 8 + lr8) * K_TOT;
            gl_lds16(Bs + r0,      Bb + (16 * wave) * 128);
            gl_lds16(Bs + r1,      Bb + (16 * wave + 8) * 128);
            gl_lds16(Bs + r0 + 64, Bb + 16384 + (16 * wave) * 128);
            gl_lds16(Bs + r1 + 64, Bb + 16384 + (16 * wave + 8) * 128);
        }
        // init pool to map(0.0f)
        {
            uint4 iv = {0x80000000u, 0x80000000u, 0x80000000u, 0x80000000u};
            uint4* P4 = (uint4*)pool;
            #pragma unroll
            for (int r = 0; r < 4; ++r) P4[tid + r * 512] = iv;
        }
        __syncthreads();                         // init visible (B also drained)

        // scatter-pool cell q: 4 entries in flight x 128 dims, 2-deep prefetch
        {
            const int dim = tid & 127;
            const int eg  = tid >> 7;
            const int n   = nq[q];
            int e  = eg;
            int p0 = (e < n)     ? (int)ml[q * MCAP + e]     : -1;
            int p1 = (e + 4 < n) ? (int)ml[q * MCAP + e + 4] : -1;
            float v0 = 0.f;
            if (p0 >= 0) v0 = hs[(size_t)(p0 >> 6) * H + dim];
            while (p0 >= 0) {
                int p2 = (e + 8 < n) ? (int)ml[q * MCAP + e + 8] : -1;
                float v1 = 0.f;
                if (p1 >= 0) v1 = hs[(size_t)(p1 >> 6) * H + dim];
                atomicMax(&pool[(p0 & 63) * H + dim], map_f2u(v0));
                e += 4; p0 = p1; p1 = p2; v0 = v1;
            }
        }
        __syncthreads();                         // pool complete

        // convert: read own chunks to regs, barrier, write swizzled bf16 Alds
        uint4 c0a, c0b, c1a, c1b;
        {
            const uint4* P4 = (const uint4*)pool;
            const int cid0 = tid, cid1 = tid + 512;
            c0a = P4[(cid0 >> 4) * 32 + (cid0 & 15) * 2];
            c0b = P4[(cid0 >> 4) * 32 + (cid0 & 15) * 2 + 1];
            c1a = P4[(cid1 >> 4) * 32 + (cid1 & 15) * 2];
            c1b = P4[(cid1 >> 4) * 32 + (cid1 & 15) * 2 + 1];
        }
        __syncthreads();                         // reads done before alias write
        {
            const int cid0 = tid, cid1 = tid + 512;
            uint4 o0, o1;
            o0.x = pack2x(c0a.x, c0a.y); o0.y = pack2x(c0a.z, c0a.w);
            o0.z = pack2x(c0b.x, c0b.y); o0.w = pack2x(c0b.z, c0b.w);
            o1.x = pack2x(c1a.x, c1a.y); o1.y = pack2x(c1a.z, c1a.w);
            o1.z = pack2x(c1b.x, c1b.y); o1.w = pack2x(c1b.z, c1b.w);
            int p0 = cid0 >> 4, ch0 = cid0 & 15;
            int p1 = cid1 >> 4, ch1 = cid1 & 15;
            *(uint4*)((char*)Alds + p0 * 256 + ((ch0 ^ (p0 & 15)) * 16)) = o0;
            *(uint4*)((char*)Alds + p1 * 256 + ((ch1 ^ (p1 & 15)) * 16)) = o1;
        }
        __syncthreads();                         // Alds + B visible everywhere

        // GEMM quarter: 2 halves x 2 k-chunks x 2mt x 2nt = 16 MFMA/wave
        #pragma unroll
        for (int h = 0; h < 2; ++h) {
            #pragma unroll
            for (int ks = 0; ks < 2; ++ks) {
                const int gch = h * 8 + ks * 4 + lh;   // A chunk in [0,16)
                const int ch  = ks * 4 + lh;           // B chunk in [0,8)
                bf16x8 af[2], bf[2];
                #pragma unroll
                for (int mt = 0; mt < 2; ++mt) {
                    int ar = wr * 32 + mt * 16 + ll_;
                    af[mt] = *(const bf16x8*)((const char*)Alds + ar * 256 +
                                              ((gch ^ (ar & 15)) * 16));
                }
                #pragma unroll
                for (int nt = 0; nt < 2; ++nt) {
                    int br = wc * 32 + nt * 16 + ll_;
                    bf[nt] = *(const bf16x8*)(Bb + h * 16384 + br * 128 +
                                              ((ch ^ (br & 7)) * 16));
                }
                #pragma unroll
                for (int mt = 0; mt < 2; ++mt)
                    #pragma unroll
                    for (int nt = 0; nt < 2; ++nt)
                        acc[mt][nt] = __builtin_amdgcn_mfma_f32_16x16x32_bf16(
                            af[mt], bf[nt], acc[mt][nt], 0, 0, 0);
            }
        }
        __syncthreads();                         // GEMM reads done before next init
    }

    // store partial (D layout: col = lane&15, row = (lane>>4)*4 + reg)
    float* dst = part + (size_t)ky * (N_PED * H);
    #pragma unroll
    for (int mt = 0; mt < 2; ++mt)
        #pragma unroll
        for (int nt = 0; nt < 2; ++nt) {
            int col   = wc * 32 + nt * 16 + ll_;
            int rbase = m0 + wr * 32 + mt * 16 + lh * 4;
            #pragma unroll
            for (int r = 0; r < 4; ++r)
                dst[(size_t)(rbase + r) * H + col] = acc[mt][nt][r];
        }
}

// out = bias + sum over KSPLIT partials
__global__ __launch_bounds__(128) void reduce_out(const float* __restrict__ part,
                                                  const float* __restrict__ b,
                                                  float* __restrict__ out) {
    const int idx = (blockIdx.x * 128 + threadIdx.x) * 4;   // 256 blocks
    float4 acc = *(const float4*)&b[idx & (H - 1)];
    #pragma unroll
    for (int s = 0; s < KSPLIT; ++s) {
        float4 p = *(const float4*)&part[(size_t)s * (N_PED * H) + idx];
        acc.x += p.x; acc.y += p.y; acc.z += p.z; acc.w += p.w;
    }
    *(float4*)&out[idx] = acc;
}

extern "C" void kernel_launch(void* const* d_in, const int* in_sizes, int n_in,
                              void* d_out, int out_size, void* d_ws, size_t ws_size,
                              hipStream_t stream) {
    const float* hs  = (const float*)d_in[0];   // [1024][128]
    const float* pos = (const float*)d_in[1];   // [1024][2]
    const float* Wm  = (const float*)d_in[2];   // [8192][128]
    const float* b   = (const float*)d_in[3];   // [128]
    float* out = (float*)d_out;                 // [1024][128]

    ushort* Wt    = (ushort*)d_ws;                              // 2 MB
    ushort* lists = (ushort*)((char*)d_ws + (2u << 20));        // 384 KB
    int*    cntg  = (int*)((char*)d_ws + (2u << 20) + (512u << 10)); // 4 KB
    float*  part  = (float*)((char*)d_ws + (3u << 20));         // 8 MB

    prep<<<192, 512, 0, stream>>>(pos, Wm, lists, cntg, Wt);
    pool_gemm<<<dim3(16, 16), 512, 0, stream>>>(hs, lists, cntg, Wt, part);
    reduce_out<<<(N_PED * H) / (128 * 4), 128, 0, stream>>>(part, b, out);
}

// Round 18
// 28.201 us; speedup vs baseline: 1.7411x; 1.7411x over previous
//
#include <hip/hip_runtime.h>
#include <hip/hip_bf16.h>

#define N_PED 1024
#define H 128
#define G 8
#define NCELL 64
#define K_TOT 8192
#define HALF_NB 16.0f
#define INV_CELL 0.25f

#define KSPLIT 16
#define KC 512          // K per gemm block
#define BM 64
#define BK 64
#define NSTAGE 8        // KC/BK

typedef __attribute__((ext_vector_type(8))) short bf16x8;
typedef __attribute__((ext_vector_type(4))) float f32x4;

__device__ __forceinline__ unsigned map_f2u(float v) {
    unsigned u = __float_as_uint(v);
    return (u & 0x80000000u) ? ~u : (u | 0x80000000u);
}
__device__ __forceinline__ ushort f2bf(float f) {   // round-to-nearest-even
    unsigned u = __float_as_uint(f);
    return (ushort)((u + 0x7FFFu + ((u >> 16) & 1u)) >> 16);
}
// pooled values are >= map(0) -> unmap is a single XOR
__device__ __forceinline__ unsigned pack2x(unsigned ua, unsigned ub) {
    float2 f = {__uint_as_float(ua ^ 0x80000000u),
                __uint_as_float(ub ^ 0x80000000u)};
    union { __hip_bfloat162 h; unsigned u; } cv;
    cv.h = __float22bfloat162_rn(f);
    return cv.u;
}
__device__ __forceinline__ unsigned pack2f(float fa, float fb) {
    float2 f = {fa, fb};
    union { __hip_bfloat162 h; unsigned u; } cv;
    cv.h = __float22bfloat162_rn(f);
    return cv.u;
}
__device__ __forceinline__ void gl_lds16(const void* g, void* l) {
    __builtin_amdgcn_global_load_lds(
        (const __attribute__((address_space(1))) void*)g,
        (__attribute__((address_space(3))) void*)l, 16, 0, 0);
}

// blocks 0..1023   : build pooled grid row (bf16 [8192]) for pedestrian i
// blocks 1024..1151: convert+transpose 64-k slab of W into Wt bf16 [128][8192]
__global__ __launch_bounds__(512) void fused_pre(const float* __restrict__ hs,
                                                 const float* __restrict__ pos,
                                                 const float* __restrict__ W,
                                                 ushort* __restrict__ grid,
                                                 ushort* __restrict__ Wt) {
    __shared__ __align__(16) char smem[36872];
    const int tid = threadIdx.x;

    if (blockIdx.x < N_PED) {
        unsigned* lgrid = (unsigned*)smem;            // 32768 B
        int*      list  = (int*)(smem + 32768);       // 4096 B
        int*      cnt   = (int*)(smem + 36864);       // 4 B
        const int i = blockIdx.x;

        const unsigned iu = 0x80000000u;              // map_f2u(0.0f)
        uint4 iv = {iu, iu, iu, iu};
        for (int k = tid; k < NCELL * H / 4; k += 512) ((uint4*)lgrid)[k] = iv;
        if (tid == 0) *cnt = 0;
        __syncthreads();

        const float2 pi = ((const float2*)pos)[i];
        for (int j = tid; j < N_PED; j += 512) {
            float2 pj = ((const float2*)pos)[j];
            float rx = pj.x - pi.x;
            float ry = pj.y - pi.y;
            if (j != i && fabsf(rx) <= HALF_NB && fabsf(ry) <= HALF_NB) {
                int gx = min(G - 1, max(0, (int)floorf((rx + HALF_NB) * INV_CELL)));
                int gy = min(G - 1, max(0, (int)floorf((ry + HALF_NB) * INV_CELL)));
                int slot = atomicAdd(cnt, 1);
                list[slot] = (j << 8) | (gy * G + gx);
            }
        }
        __syncthreads();

        // pooling: 16-way entry parallel; lane c owns dims {c,c+32,c+64,c+96}
        // -> atomic bank = c: conflict-free across the 32-lane group (m136)
        const int n  = *cnt;
        const int c  = tid & 31;
        const int eg = tid >> 5;                      // 0..15
        int e  = eg;
        int p0 = (e < n) ? list[e] : -1;
        int p1 = (e + 16 < n) ? list[e + 16] : -1;
        float v0[4] = {};
        if (p0 >= 0) {
            const float* hp = &hs[(p0 >> 8) * H + c];
            v0[0] = hp[0]; v0[1] = hp[32]; v0[2] = hp[64]; v0[3] = hp[96];
        }
        while (p0 >= 0) {
            int p2 = (e + 32 < n) ? list[e + 32] : -1;
            float v1[4] = {};
            if (p1 >= 0) {
                const float* hp = &hs[(p1 >> 8) * H + c];
                v1[0] = hp[0]; v1[1] = hp[32]; v1[2] = hp[64]; v1[3] = hp[96];
            }
            unsigned* gph = &lgrid[(p0 & 255) * H + c];
            atomicMax(gph + 0,  map_f2u(v0[0]));
            atomicMax(gph + 32, map_f2u(v0[1]));
            atomicMax(gph + 64, map_f2u(v0[2]));
            atomicMax(gph + 96, map_f2u(v0[3]));
            e += 16; p0 = p1; p1 = p2;
            v0[0] = v1[0]; v0[1] = v1[1]; v0[2] = v1[2]; v0[3] = v1[3];
        }
        __syncthreads();

        // writeout: consecutive-lane b128 reads (conflict-free), uint2 stores
        uint2* dst2 = (uint2*)(grid + (size_t)i * K_TOT);
        for (int q = tid; q < K_TOT / 4; q += 512) {   // 2048 uint4 total
            uint4 a = ((const uint4*)lgrid)[q];
            uint2 o;
            o.x = pack2x(a.x, a.y);
            o.y = pack2x(a.z, a.w);
            dst2[q] = o;
        }
    } else {
        float* tile = (float*)smem;                   // [64][129] = 33024 B
        const int bw  = blockIdx.x - N_PED;
        const int k0w = bw * 64;

        for (int x = tid; x < 64 * H; x += 512) {
            int r = x >> 7, cc = x & 127;
            tile[r * 129 + cc] = W[(size_t)(k0w + r) * H + cc];
        }
        __syncthreads();

        const int col = tid >> 2;                     // 0..127
        const int kh  = (tid & 3) * 16;
        uint tmp[8];
        #pragma unroll
        for (int t = 0; t < 8; ++t)
            tmp[t] = pack2f(tile[(kh + 2 * t) * 129 + col],
                            tile[(kh + 2 * t + 1) * 129 + col]);
        uint4* w0 = (uint4*)(Wt + (size_t)col * K_TOT + k0w + kh);
        w0[0] = *(const uint4*)&tmp[0];
        w0[1] = *(const uint4*)&tmp[4];
    }
}

// A[1024][8192] bf16 @ Wt[128][8192] bf16 -> part [KSPLIT][1024][128] BF16
// (halves intermediate traffic vs fp32; bf16 partial rounding adds ~0.004
// absmax, 3x headroom remains). BM=64, 512 thr (8 waves, 2m x 4n).
// Triple-buffered LDS, counted vmcnt(3), chunk-XOR swizzle both sides.
__global__ __launch_bounds__(512) void gemm_mfma(const ushort* __restrict__ A,
                                                 const ushort* __restrict__ Wt,
                                                 ushort* __restrict__ part) {
    __shared__ ushort sA[3][BM * BK];   // 3 x 8 KB
    __shared__ ushort sB[3][H * BK];    // 3 x 16 KB

    const int m0   = blockIdx.x * BM;
    const int k0   = blockIdx.y * KC;
    const int tid  = threadIdx.x;
    const int wave = tid >> 6;
    const int lane = tid & 63;
    const int ll   = lane & 15;
    const int lh   = lane >> 4;
    const int lr8  = lane >> 3;                 // 0..7 row-in-group
    const int cswz = (lane & 7) ^ (lr8 & 7);    // swizzled chunk to fetch
    const int wr   = wave >> 2;                 // 0..1  (m half)
    const int wc   = wave & 3;                  // 0..3  (n quarter)

    const ushort* Abase = A  + (size_t)(m0 + 8 * wave + lr8) * K_TOT + k0 + cswz * 8;
    const ushort* Bbase = Wt + (size_t)(16 * wave + lr8) * K_TOT     + k0 + cswz * 8;

    f32x4 acc[2][2] = {};   // [mt][nt]

#define STAGE(T, BUF)                                                          \
    do {                                                                       \
        gl_lds16(Abase + (T) * BK, &sA[BUF][(8 * wave) * BK]);                 \
        gl_lds16(Bbase + (T) * BK,              &sB[BUF][(16 * wave) * BK]);   \
        gl_lds16(Bbase + (T) * BK + 8 * K_TOT,  &sB[BUF][(16 * wave + 8) * BK]); \
    } while (0)

    STAGE(0, 0);
    STAGE(1, 1);
    asm volatile("s_waitcnt vmcnt(3)" ::: "memory");
    __builtin_amdgcn_s_barrier();

    #pragma unroll
    for (int t = 0; t < NSTAGE; ++t) {
        if (t + 2 < NSTAGE) STAGE(t + 2, (t + 2) % 3);

        const int buf = t % 3;
        #pragma unroll
        for (int ks = 0; ks < 2; ++ks) {
            const int ch = ks * 4 + lh;         // 16B chunk index in BK
            bf16x8 afrag[2], bfrag[2];
            #pragma unroll
            for (int mt = 0; mt < 2; ++mt) {
                int ar = wr * 32 + mt * 16 + ll;
                afrag[mt] = *(const bf16x8*)&sA[buf][ar * BK + ((ch ^ (ar & 7)) * 8)];
            }
            #pragma unroll
            for (int nt = 0; nt < 2; ++nt) {
                int br = wc * 32 + nt * 16 + ll;
                bfrag[nt] = *(const bf16x8*)&sB[buf][br * BK + ((ch ^ (br & 7)) * 8)];
            }
            #pragma unroll
            for (int mt = 0; mt < 2; ++mt)
                #pragma unroll
                for (int nt = 0; nt < 2; ++nt)
                    acc[mt][nt] = __builtin_amdgcn_mfma_f32_16x16x32_bf16(
                        afrag[mt], bfrag[nt], acc[mt][nt], 0, 0, 0);
        }

        if (t + 1 < NSTAGE) {
            if (t + 2 < NSTAGE)
                asm volatile("s_waitcnt vmcnt(3)" ::: "memory");
            else
                asm volatile("s_waitcnt vmcnt(0)" ::: "memory");
            __builtin_amdgcn_s_barrier();
        }
    }
#undef STAGE

    // store bf16 partial (D layout: col = lane&15, row = (lane>>4)*4 + reg)
    ushort* dst = part + (size_t)blockIdx.y * (N_PED * H);
    #pragma unroll
    for (int mt = 0; mt < 2; ++mt)
        #pragma unroll
        for (int nt = 0; nt < 2; ++nt) {
            int col   = wc * 32 + nt * 16 + ll;
            int rbase = m0 + wr * 32 + mt * 16 + lh * 4;
            #pragma unroll
            for (int r = 0; r < 4; ++r)
                dst[(size_t)(rbase + r) * H + col] = f2bf(acc[mt][nt][r]);
        }
}

// out = bias + sum over KSPLIT bf16 partials (fp32 accumulate)
__global__ __launch_bounds__(128) void reduce_out(const ushort* __restrict__ part,
                                                  const float* __restrict__ b,
                                                  float* __restrict__ out) {
    const int idx = (blockIdx.x * 128 + threadIdx.x) * 4;   // 256 blocks
    float4 acc = *(const float4*)&b[idx & (H - 1)];
    #pragma unroll
    for (int s = 0; s < KSPLIT; ++s) {
        uint2 p = *(const uint2*)&part[(size_t)s * (N_PED * H) + idx];
        acc.x += __uint_as_float(p.x << 16);
        acc.y += __uint_as_float(p.x & 0xFFFF0000u);
        acc.z += __uint_as_float(p.y << 16);
        acc.w += __uint_as_float(p.y & 0xFFFF0000u);
    }
    *(float4*)&out[idx] = acc;
}

extern "C" void kernel_launch(void* const* d_in, const int* in_sizes, int n_in,
                              void* d_out, int out_size, void* d_ws, size_t ws_size,
                              hipStream_t stream) {
    const float* hs  = (const float*)d_in[0];   // [1024][128]
    const float* pos = (const float*)d_in[1];   // [1024][2]
    const float* Wm  = (const float*)d_in[2];   // [8192][128]
    const float* b   = (const float*)d_in[3];   // [128]
    float* out = (float*)d_out;                 // [1024][128]

    ushort* grid = (ushort*)d_ws;                               // 16 MB
    ushort* Wt   = (ushort*)((char*)d_ws + (16u << 20));        // 2 MB
    ushort* part = (ushort*)((char*)d_ws + (18u << 20));        // 4 MB bf16

    fused_pre<<<N_PED + 128, 512, 0, stream>>>(hs, pos, Wm, grid, Wt);
    gemm_mfma<<<dim3(N_PED / BM, KSPLIT), 512, 0, stream>>>(grid, Wt, part);
    reduce_out<<<(N_PED * H) / (128 * 4), 128, 0, stream>>>(part, b, out);
}